// Round 9
// baseline (108.367 us; speedup 1.0000x reference)
//
#include <hip/hip_runtime.h>

#define RADIUS 5
#define TILEX  32                   // output px per block in x
#define TILEY  16                   // output px per block in y
#define HX     (TILEX + 2*RADIUS)   // 42
#define HY     (TILEY + 2*RADIUS)   // 26
#define HPITCH 21                   // half-columns per row (42/2), odd
#define H      256
#define W      256
#define NREP   4                    // PROBE: x4 internal rep to surface counters

// exp2-folded Mahalanobis coefficients kappa = -0.5*log2(e)*sigma_inv:
// ch0-1 (sigma 10.0), ch2-4 (0.02), ch5-7 (0.1)
#define KA (-0.072134752f)
#define KB (-36.06737602f)
#define KC (-7.213475204f)

struct Center { float4 hA, hB; float phic; };

__device__ __forceinline__ void accum(const float4 A, const float4 G, const float4 P,
                                      const Center& C, const float gate,
                                      float& sw, float& ax, float& ay, float& az) {
    const float t = P.w + C.phic
                  + C.hA.x*A.x + C.hA.y*A.y + C.hA.z*A.z + C.hA.w*A.w
                  + C.hB.x*G.x + C.hB.y*G.y + C.hB.z*G.z + C.hB.w*G.w;
    const float w = gate * __builtin_amdgcn_exp2f(t);
    sw += w; ax += w * P.x; ay += w * P.y; az += w * P.z;
}

// R9 = R8 kernel with an outer NREP loop (idempotent) so the kernel becomes the
// LONGEST dispatch and finally shows its rocprof counters. Structure unchanged.
__global__ __launch_bounds__(512, 2) void jbf_kernel(
    const float* __restrict__ image,     // (B,3,H,W)
    const float* __restrict__ guidance,  // (B,8,H,W)
    float* __restrict__ out)             // (B,3,H,W)
{
    __shared__ float4 g0e[HY * HPITCH], g0o[HY * HPITCH];  // guidance ch0-3
    __shared__ float4 g1e[HY * HPITCH], g1o[HY * HPITCH];  // guidance ch4-7
    __shared__ float4 ime[HY * HPITCH], imo[HY * HPITCH];  // image ch0-2 + phi

    const int b       = blockIdx.z;
    const int tile_x0 = blockIdx.x * TILEX;
    const int tile_y0 = blockIdx.y * TILEY;
    const int txp     = threadIdx.x;        // 0..15 (lane bits 0-3)
    const int h       = threadIdx.y;        // 0..3  (lane bits 4-5)
    const int typ     = threadIdx.z;        // 0..7  (wave id)
    const int tid     = (typ * 4 + h) * 16 + txp;

    const float* gbase = guidance + (size_t)b * 8 * H * W;
    const float* ibase = image    + (size_t)b * 3 * H * W;

    for (int rep = 0; rep < NREP; ++rep) {
        __syncthreads();   // reps>0: prior readers done before re-staging

        for (int idx = tid; idx < HX * HY; idx += 512) {
            const int ly = idx / HX;
            const int lx = idx - ly * HX;
            int gy = tile_y0 - RADIUS + ly;
            int gx = tile_x0 - RADIUS + lx;
            gy = (gy < 0) ? -gy : ((gy >= H) ? 2 * (H - 1) - gy : gy);
            gx = (gx < 0) ? -gx : ((gx >= W) ? 2 * (W - 1) - gx : gx);
            const int off = gy * W + gx;
            const int l   = ly * HPITCH + (lx >> 1);
            const float4 v0 = make_float4(gbase[0*H*W+off], gbase[1*H*W+off],
                                          gbase[2*H*W+off], gbase[3*H*W+off]);
            const float4 v1 = make_float4(gbase[4*H*W+off], gbase[5*H*W+off],
                                          gbase[6*H*W+off], gbase[7*H*W+off]);
            const float phi = KA * (v0.x*v0.x + v0.y*v0.y)
                            + KB * (v0.z*v0.z + v0.w*v0.w + v1.x*v1.x)
                            + KC * (v1.y*v1.y + v1.z*v1.z + v1.w*v1.w);
            const float4 vi = make_float4(ibase[0*H*W+off], ibase[1*H*W+off],
                                          ibase[2*H*W+off], phi);
            if (lx & 1) { g0o[l] = v0; g1o[l] = v1; imo[l] = vi; }
            else        { g0e[l] = v0; g1e[l] = v1; ime[l] = vi; }
        }
        __syncthreads();

        Center c[2][2];
        #pragma unroll
        for (int cy = 0; cy < 2; ++cy) {
            const int row = (2 * typ + 5 + cy) * HPITCH;
            #pragma unroll
            for (int cx = 0; cx < 2; ++cx) {
                const int ci = row + txp + 2 + cx;
                const float4 gA = cx ? g0e[ci] : g0o[ci];
                const float4 gB = cx ? g1e[ci] : g1o[ci];
                const float4 pv = cx ? ime[ci] : imo[ci];
                c[cx][cy].hA = make_float4(-2.f*KA*gA.x, -2.f*KA*gA.y,
                                           -2.f*KB*gA.z, -2.f*KB*gA.w);
                c[cx][cy].hB = make_float4(-2.f*KB*gB.x, -2.f*KC*gB.y,
                                           -2.f*KC*gB.z, -2.f*KC*gB.w);
                c[cx][cy].phic = pv.w;
            }
        }

        float s[2][2]  = {{0.f,0.f},{0.f,0.f}};
        float ax[2][2] = {{0.f,0.f},{0.f,0.f}};
        float ay[2][2] = {{0.f,0.f},{0.f,0.f}};
        float az[2][2] = {{0.f,0.f},{0.f,0.f}};

        #pragma unroll
        for (int i = 0; i < 3; ++i) {
            const int r  = 4 * i + h;
            const int rb = (2 * typ + r) * HPITCH + txp;
            const float fy0 = (r <= 10) ? 1.0f : 0.0f;
            const float fy1 = (r >= 1)  ? 1.0f : 0.0f;
            #pragma unroll
            for (int k = 0; k <= 5; ++k) {
                {   // EVEN columns
                    const float4 A = g0e[rb + k], G = g1e[rb + k], P = ime[rb + k];
                    accum(A, G, P, c[0][0], fy0, s[0][0], ax[0][0], ay[0][0], az[0][0]);
                    accum(A, G, P, c[0][1], fy1, s[0][1], ax[0][1], ay[0][1], az[0][1]);
                    if (k >= 1) {
                        accum(A, G, P, c[1][0], fy0, s[1][0], ax[1][0], ay[1][0], az[1][0]);
                        accum(A, G, P, c[1][1], fy1, s[1][1], ax[1][1], ay[1][1], az[1][1]);
                    }
                }
                {   // ODD columns
                    const float4 A = g0o[rb + k], G = g1o[rb + k], P = imo[rb + k];
                    if (k <= 4) {
                        accum(A, G, P, c[0][0], fy0, s[0][0], ax[0][0], ay[0][0], az[0][0]);
                        accum(A, G, P, c[0][1], fy1, s[0][1], ax[0][1], ay[0][1], az[0][1]);
                    }
                    accum(A, G, P, c[1][0], fy0, s[1][0], ax[1][0], ay[1][0], az[1][0]);
                    accum(A, G, P, c[1][1], fy1, s[1][1], ax[1][1], ay[1][1], az[1][1]);
                }
            }
        }

        #pragma unroll
        for (int cx = 0; cx < 2; ++cx)
            #pragma unroll
            for (int cy = 0; cy < 2; ++cy) {
                s[cx][cy]  += __shfl_xor(s[cx][cy], 16);  s[cx][cy]  += __shfl_xor(s[cx][cy], 32);
                ax[cx][cy] += __shfl_xor(ax[cx][cy], 16); ax[cx][cy] += __shfl_xor(ax[cx][cy], 32);
                ay[cx][cy] += __shfl_xor(ay[cx][cy], 16); ay[cx][cy] += __shfl_xor(ay[cx][cy], 32);
                az[cx][cy] += __shfl_xor(az[cx][cy], 16); az[cx][cy] += __shfl_xor(az[cx][cy], 32);
            }

        if (h == 0) {
            const size_t base = (size_t)b * 3 * H * W
                              + (size_t)(tile_y0 + 2 * typ) * W + (tile_x0 + 2 * txp);
            #pragma unroll
            for (int cy = 0; cy < 2; ++cy) {
                const float i0 = 1.0f / s[0][cy];
                const float i1 = 1.0f / s[1][cy];
                float2* __restrict__ o2 = (float2*)(out + base + (size_t)cy * W);
                o2[0]           = make_float2(ax[0][cy] * i0, ax[1][cy] * i1);
                o2[(H*W) / 2]   = make_float2(ay[0][cy] * i0, ay[1][cy] * i1);
                o2[(2*H*W) / 2] = make_float2(az[0][cy] * i0, az[1][cy] * i1);
            }
        }
    }
}

extern "C" void kernel_launch(void* const* d_in, const int* in_sizes, int n_in,
                              void* d_out, int out_size, void* d_ws, size_t ws_size,
                              hipStream_t stream) {
    const float* image    = (const float*)d_in[0];
    const float* guidance = (const float*)d_in[1];
    float* out            = (float*)d_out;

    const int B = in_sizes[0] / (3 * H * W);   // = 2
    dim3 grid(W / TILEX, H / TILEY, B);        // 8 x 16 x 2 = 256 blocks
    dim3 block(16, 4, 8);                      // 512 threads = 8 waves
    hipLaunchKernelGGL(jbf_kernel, grid, block, 0, stream, image, guidance, out);
}